// Round 12
// baseline (560.025 us; speedup 1.0000x reference)
//
#include <hip/hip_runtime.h>
#include <hip/hip_fp16.h>
#include <hip/hip_cooperative_groups.h>
#include <cstdint>
#include <cstddef>

namespace cg = cooperative_groups;

#define NNODES 50000
#define NEDGES 800000
#define NGRAPH 64
#define BCAP 128
#define GEMM_BLKS ((NNODES + 63) / 64)        // 782
#define SCAT_BLKS ((NEDGES / 4 + 255) / 256)  // 782 (4 edges per thread)
#define GRID_MAX 768

typedef __attribute__((ext_vector_type(8))) _Float16 half8;
typedef __attribute__((ext_vector_type(4))) float float4v;

__device__ __forceinline__ float lrelu(float x) { return x > 0.f ? x : 0.2f * x; }

struct KArgs {
    const float* x; const int* src; const int* dst; const int* batch;
    const float *W1, *as1, *ad1, *b1;
    const float *W2, *as2, *ad2, *b2;
    const float *Wp, *asp, *adp, *bp;
    const float *Wh1, *bh1, *Wh2, *bh2;
    float* out;
    _Float16 *ha16, *hb16, *projh, *w1t, *w2t, *wpt;
    float *asn, *adn;
    int *cnt, *bucket;
};

// ---------- MFMA GEMM tile (64 rows) + fused attention scores ----------
template <int NFRAG>
__device__ __forceinline__ void gemm_body(const _Float16* __restrict__ A,
                                          const _Float16* __restrict__ Wt,
                                          const float* __restrict__ a_src,
                                          const float* __restrict__ a_dst,
                                          _Float16* __restrict__ C,
                                          float* __restrict__ as_n,
                                          float* __restrict__ ad_n,
                                          int M, int K, int blk, bool f32a,
                                          const float* __restrict__ A32) {
    constexpr int N = NFRAG * 16;
    constexpr int H = NFRAG / 4;
    const int w = threadIdx.x >> 6;
    const int lane = threadIdx.x & 63;
    const int quad = lane >> 4;
    const int mcol = lane & 15;
    int arow = blk * 64 + w * 16 + mcol;
    if (arow >= M) arow = M - 1;
    const _Float16* bp = Wt + (size_t)mcol * K + quad * 8;
    float4v acc[NFRAG];
#pragma unroll
    for (int nf = 0; nf < NFRAG; ++nf) acc[nf] = (float4v)0.f;
    if (f32a) {
        const float* ap = A32 + (size_t)arow * K + quad * 8;
        for (int kt = 0; kt < K; kt += 32) {
            float4 a0 = *reinterpret_cast<const float4*>(ap + kt);
            float4 a1 = *reinterpret_cast<const float4*>(ap + kt + 4);
            half8 a;
            a[0] = (_Float16)a0.x; a[1] = (_Float16)a0.y;
            a[2] = (_Float16)a0.z; a[3] = (_Float16)a0.w;
            a[4] = (_Float16)a1.x; a[5] = (_Float16)a1.y;
            a[6] = (_Float16)a1.z; a[7] = (_Float16)a1.w;
#pragma unroll
            for (int nf = 0; nf < NFRAG; ++nf) {
                half8 b = *reinterpret_cast<const half8*>(bp + (size_t)nf * 16 * K + kt);
                acc[nf] = __builtin_amdgcn_mfma_f32_16x16x32_f16(a, b, acc[nf], 0, 0, 0);
            }
        }
    } else {
        const _Float16* ap = A + (size_t)arow * K + quad * 8;
        for (int kt = 0; kt < K; kt += 32) {
            half8 a = *reinterpret_cast<const half8*>(ap + kt);
#pragma unroll
            for (int nf = 0; nf < NFRAG; ++nf) {
                half8 b = *reinterpret_cast<const half8*>(bp + (size_t)nf * 16 * K + kt);
                acc[nf] = __builtin_amdgcn_mfma_f32_16x16x32_f16(a, b, acc[nf], 0, 0, 0);
            }
        }
    }
    const int orow0 = blk * 64 + w * 16 + quad * 4;
#pragma unroll
    for (int r = 0; r < 4; ++r) {
        int orow = orow0 + r;
        if (orow < M) {
            _Float16* crow = C + (size_t)orow * N + mcol;
#pragma unroll
            for (int nf = 0; nf < NFRAG; ++nf) crow[nf * 16] = (_Float16)acc[nf][r];
        }
    }
    float ps[H][4], pd[H][4];
#pragma unroll
    for (int hd = 0; hd < H; ++hd)
#pragma unroll
        for (int r = 0; r < 4; ++r) { ps[hd][r] = 0.f; pd[hd][r] = 0.f; }
#pragma unroll
    for (int nf = 0; nf < NFRAG; ++nf) {
        float asv = a_src[nf * 16 + mcol];
        float adv = a_dst[nf * 16 + mcol];
#pragma unroll
        for (int r = 0; r < 4; ++r) {
            ps[nf >> 2][r] = fmaf(acc[nf][r], asv, ps[nf >> 2][r]);
            pd[nf >> 2][r] = fmaf(acc[nf][r], adv, pd[nf >> 2][r]);
        }
    }
#pragma unroll
    for (int off = 1; off < 16; off <<= 1) {
#pragma unroll
        for (int hd = 0; hd < H; ++hd)
#pragma unroll
            for (int r = 0; r < 4; ++r) {
                ps[hd][r] += __shfl_xor(ps[hd][r], off);
                pd[hd][r] += __shfl_xor(pd[hd][r], off);
            }
    }
    if (mcol == 0) {
#pragma unroll
        for (int r = 0; r < 4; ++r) {
            int orow = orow0 + r;
            if (orow < M) {
#pragma unroll
                for (int hd = 0; hd < H; ++hd) {
                    as_n[orow * H + hd] = ps[hd][r];
                    ad_n[orow * H + hd] = pd[hd][r];
                }
            }
        }
    }
}

// ---------- per-node ONLINE softmax + aggregation (grid-stride) ----------
template <int H, bool HALF_OUT>
__device__ __forceinline__ void agg_phase(const int* __restrict__ bucket,
                                          const int* __restrict__ cntp,
                                          const __half* __restrict__ h,
                                          const float* __restrict__ asn,
                                          const float* __restrict__ adn,
                                          const float* __restrict__ bias,
                                          void* __restrict__ outv) {
    constexpr int HC = H * 64;
    constexpr int VPL = HC / 64;
    constexpr int EPC = 64 / H;
    const int lane = threadIdx.x & 63;
    const int hd = (H == 4) ? (lane >> 4) : 0;
    const int ej = (H == 4) ? (lane & 15) : lane;
    const int base = (H == 4) ? (lane & 48) : 0;
    for (int n = blockIdx.x * 4 + (threadIdx.x >> 6); n < NNODES; n += gridDim.x * 4) {
        const int rs = n * BCAP;
        const int re = rs + min(cntp[n], BCAP);
        const float ad = adn[n * H + hd];
        const float es = lrelu(asn[n * H + hd] + ad);
        float m = es;
        float denp = (ej == 0) ? 1.f : 0.f;
        float acc0, acc1, acc2, acc3;
        if (VPL == 4) {
            uint2 u = *reinterpret_cast<const uint2*>(&h[(size_t)n * HC + lane * 4]);
            float2 f0 = __half22float2(*reinterpret_cast<__half2*>(&u.x));
            float2 f1 = __half22float2(*reinterpret_cast<__half2*>(&u.y));
            acc0 = f0.x; acc1 = f0.y; acc2 = f1.x; acc3 = f1.y;
        } else {
            acc0 = __half2float(h[(size_t)n * HC + lane]);
            acc1 = acc2 = acc3 = 0.f;
        }
        auto body = [&](int j, float e, int s) {
            float ex = __shfl(e, base + j);
            int sj = __shfl(s, base + j);
            if (VPL == 4) {
                uint2 u = *reinterpret_cast<const uint2*>(&h[(size_t)sj * HC + lane * 4]);
                float2 f0 = __half22float2(*reinterpret_cast<__half2*>(&u.x));
                float2 f1 = __half22float2(*reinterpret_cast<__half2*>(&u.y));
                acc0 = fmaf(ex, f0.x, acc0);
                acc1 = fmaf(ex, f0.y, acc1);
                acc2 = fmaf(ex, f1.x, acc2);
                acc3 = fmaf(ex, f1.y, acc3);
            } else {
                acc0 = fmaf(ex, __half2float(h[(size_t)sj * HC + lane]), acc0);
            }
        };
        for (int c = rs; c < re; c += EPC) {
            int i = c + ej;
            int s = 0;
            float e = -1e30f;
            if (i < re) {
                s = bucket[i];
                e = lrelu(asn[s * H + hd] + ad);
            }
            float cm = e;
#pragma unroll
            for (int off = 1; off < EPC; off <<= 1) cm = fmaxf(cm, __shfl_xor(cm, off));
            float mn = fmaxf(m, cm);
            float scale = __expf(m - mn);
            m = mn;
            denp *= scale;
            acc0 *= scale; acc1 *= scale; acc2 *= scale; acc3 *= scale;
            float ex = __expf(e - m);
            denp += ex;
            const int cnt2 = min(EPC, re - c);
            if constexpr (EPC == 16) {
                if (cnt2 == 16) {
#pragma unroll
                    for (int j = 0; j < 16; ++j) body(j, ex, s);
                } else {
                    for (int j = 0; j < cnt2; ++j) body(j, ex, s);
                }
            } else {
#pragma unroll 8
                for (int j = 0; j < cnt2; ++j) body(j, ex, s);
            }
        }
        float den = denp;
#pragma unroll
        for (int off = 1; off < EPC; off <<= 1) den += __shfl_xor(den, off);
        const float inv = 1.f / (den + 1e-16f);
        if (VPL == 4) {
            float v0 = acc0 * inv + bias[lane * 4 + 0];
            float v1 = acc1 * inv + bias[lane * 4 + 1];
            float v2 = acc2 * inv + bias[lane * 4 + 2];
            float v3 = acc3 * inv + bias[lane * 4 + 3];
            v0 = v0 > 0.f ? v0 : expm1f(v0);
            v1 = v1 > 0.f ? v1 : expm1f(v1);
            v2 = v2 > 0.f ? v2 : expm1f(v2);
            v3 = v3 > 0.f ? v3 : expm1f(v3);
            if constexpr (HALF_OUT) {
                union { _Float16 h4[4]; uint2 u; } r;
                r.h4[0] = (_Float16)v0; r.h4[1] = (_Float16)v1;
                r.h4[2] = (_Float16)v2; r.h4[3] = (_Float16)v3;
                reinterpret_cast<uint2*>((_Float16*)outv + (size_t)n * HC)[lane] = r.u;
            } else {
                float4 o = make_float4(v0, v1, v2, v3);
                *reinterpret_cast<float4*>((float*)outv + (size_t)n * HC + lane * 4) = o;
            }
        } else {
            float v = acc0 * inv + bias[lane];
            v = v > 0.f ? v : expm1f(v);
            if constexpr (HALF_OUT)
                ((_Float16*)outv)[(size_t)n * HC + lane] = (_Float16)v;
            else
                ((float*)outv)[(size_t)n * HC + lane] = v;
        }
    }
}

__device__ __forceinline__ void wtrans_elem(const float* __restrict__ W,
                                            _Float16* __restrict__ Wt,
                                            int K, int N, int i) {
    int k = i / N, n = i - k * N;
    Wt[(size_t)n * K + k] = (_Float16)W[i];
}

__device__ __forceinline__ void prep_phase(const KArgs& a) {
    for (int i = blockIdx.x * 256 + threadIdx.x; i < 114688 + NNODES; i += gridDim.x * 256) {
        if (i < 32768) wtrans_elem(a.W1, a.w1t, 128, 256, i);
        else if (i < 98304) wtrans_elem(a.W2, a.w2t, 256, 256, i - 32768);
        else if (i < 114688) wtrans_elem(a.Wp, a.wpt, 256, 64, i - 98304);
        else a.cnt[i - 114688] = 0;
    }
}

__device__ __forceinline__ void g1s_phase(const KArgs& a) {
    for (int t = blockIdx.x; t < GEMM_BLKS + SCAT_BLKS; t += gridDim.x) {
        if (t < GEMM_BLKS) {
            gemm_body<16>(nullptr, a.w1t, a.as1, a.ad1, a.ha16, a.asn, a.adn,
                          NNODES, 128, t, true, a.x);
        } else {
            int e4 = (t - GEMM_BLKS) * 256 + threadIdx.x;
            if (e4 < NEDGES / 4) {
                int4 d4 = reinterpret_cast<const int4*>(a.dst)[e4];
                int4 s4 = reinterpret_cast<const int4*>(a.src)[e4];
                int p0 = atomicAdd(&a.cnt[d4.x], 1);
                int p1 = atomicAdd(&a.cnt[d4.y], 1);
                int p2 = atomicAdd(&a.cnt[d4.z], 1);
                int p3 = atomicAdd(&a.cnt[d4.w], 1);
                if (p0 < BCAP) a.bucket[(size_t)d4.x * BCAP + p0] = s4.x;
                if (p1 < BCAP) a.bucket[(size_t)d4.y * BCAP + p1] = s4.y;
                if (p2 < BCAP) a.bucket[(size_t)d4.z * BCAP + p2] = s4.z;
                if (p3 < BCAP) a.bucket[(size_t)d4.w * BCAP + p3] = s4.w;
            }
        }
    }
}

__device__ __forceinline__ void pool_phase(const KArgs& a) {
    if (blockIdx.x >= NGRAPH) return;
    __shared__ float swsum[4][64];
    __shared__ float smean[64];
    __shared__ float shid[64];
    const int tid = threadIdx.x;
    const int g = blockIdx.x;
    const int lane = tid & 63;
    const int w = tid >> 6;
    int lo = 0, hi = NNODES;
    while (lo < hi) { int mid = (lo + hi) >> 1; if (a.batch[mid] < g) lo = mid + 1; else hi = mid; }
    const int start = lo;
    hi = NNODES;
    while (lo < hi) { int mid = (lo + hi) >> 1; if (a.batch[mid] < g + 1) lo = mid + 1; else hi = mid; }
    const int end = lo;
    float acc = 0.f;
    const __half* feat = (const __half*)a.projh;
    for (int n = start + w; n < end; n += 4) acc += __half2float(feat[(size_t)n * 64 + lane]);
    swsum[w][lane] = acc;
    __syncthreads();
    if (w == 0) {
        float s = swsum[0][lane] + swsum[1][lane] + swsum[2][lane] + swsum[3][lane];
        float c = (float)(end - start);
        c = c > 1.f ? c : 1.f;
        smean[lane] = s / c;
    }
    __syncthreads();
    if (tid < 64) {
        float v = a.bh1[tid];
        for (int k = 0; k < 64; ++k) v = fmaf(smean[k], a.Wh1[k * 64 + tid], v);
        shid[tid] = v > 0.f ? v : 0.f;
    }
    __syncthreads();
    if (tid < 10) {
        float v = a.bh2[tid];
        for (int k = 0; k < 64; ++k) v = fmaf(shid[k], a.Wh2[k * 10 + tid], v);
        a.out[g * 10 + tid] = v;
    }
}

// ---------- the whole pipeline as one cooperative kernel ----------
__global__ __launch_bounds__(256) void mega(KArgs a) {
    cg::grid_group grid = cg::this_grid();
    prep_phase(a);
    grid.sync();
    g1s_phase(a);
    grid.sync();
    agg_phase<4, true>(a.bucket, a.cnt, (const __half*)a.ha16, a.asn, a.adn, a.b1, a.hb16);
    grid.sync();
    for (int t = blockIdx.x; t < GEMM_BLKS; t += gridDim.x)
        gemm_body<16>(a.hb16, a.w2t, a.as2, a.ad2, a.ha16, a.asn, a.adn,
                      NNODES, 256, t, false, nullptr);
    grid.sync();
    agg_phase<4, true>(a.bucket, a.cnt, (const __half*)a.ha16, a.asn, a.adn, a.b2, a.hb16);
    grid.sync();
    for (int t = blockIdx.x; t < GEMM_BLKS; t += gridDim.x)
        gemm_body<4>(a.hb16, a.wpt, a.asp, a.adp, a.ha16, a.asn, a.adn,
                     NNODES, 256, t, false, nullptr);
    grid.sync();
    agg_phase<1, true>(a.bucket, a.cnt, (const __half*)a.ha16, a.asn, a.adn, a.bp, a.projh);
    grid.sync();
    pool_phase(a);
}

// ---------- fallback: per-phase kernels (R10-equivalent, known-good) ----------
__global__ __launch_bounds__(256) void k_prep(KArgs a) { prep_phase(a); }
__global__ __launch_bounds__(256) void k_g1s(KArgs a)  { g1s_phase(a); }
__global__ __launch_bounds__(256) void k_gemm2(KArgs a) {
    for (int t = blockIdx.x; t < GEMM_BLKS; t += gridDim.x)
        gemm_body<16>(a.hb16, a.w2t, a.as2, a.ad2, a.ha16, a.asn, a.adn,
                      NNODES, 256, t, false, nullptr);
}
__global__ __launch_bounds__(256) void k_gemmp(KArgs a) {
    for (int t = blockIdx.x; t < GEMM_BLKS; t += gridDim.x)
        gemm_body<4>(a.hb16, a.wpt, a.asp, a.adp, a.ha16, a.asn, a.adn,
                     NNODES, 256, t, false, nullptr);
}
__global__ __launch_bounds__(256) void k_agg1(KArgs a) {
    agg_phase<4, true>(a.bucket, a.cnt, (const __half*)a.ha16, a.asn, a.adn, a.b1, a.hb16);
}
__global__ __launch_bounds__(256) void k_agg2(KArgs a) {
    agg_phase<4, true>(a.bucket, a.cnt, (const __half*)a.ha16, a.asn, a.adn, a.b2, a.hb16);
}
__global__ __launch_bounds__(256) void k_aggp(KArgs a) {
    agg_phase<1, true>(a.bucket, a.cnt, (const __half*)a.ha16, a.asn, a.adn, a.bp, a.projh);
}
__global__ __launch_bounds__(256) void k_pool(KArgs a) { pool_phase(a); }

extern "C" void kernel_launch(void* const* d_in, const int* in_sizes, int n_in,
                              void* d_out, int out_size, void* d_ws, size_t ws_size,
                              hipStream_t stream) {
    KArgs a;
    a.x   = (const float*)d_in[0];
    a.src = (const int*)d_in[1];
    a.dst = (const int*)d_in[2];
    a.batch = (const int*)d_in[3];
    a.W1 = (const float*)d_in[4];  a.as1 = (const float*)d_in[5];
    a.ad1 = (const float*)d_in[6]; a.b1 = (const float*)d_in[7];
    a.W2 = (const float*)d_in[8];  a.as2 = (const float*)d_in[9];
    a.ad2 = (const float*)d_in[10]; a.b2 = (const float*)d_in[11];
    a.Wp = (const float*)d_in[12]; a.asp = (const float*)d_in[13];
    a.adp = (const float*)d_in[14]; a.bp = (const float*)d_in[15];
    a.Wh1 = (const float*)d_in[16]; a.bh1 = (const float*)d_in[17];
    a.Wh2 = (const float*)d_in[18]; a.bh2 = (const float*)d_in[19];
    a.out = (float*)d_out;

    _Float16* hbase = (_Float16*)d_ws;
    const size_t NHC = (size_t)NNODES * 256;
    a.ha16  = hbase;
    a.hb16  = a.ha16 + NHC;
    a.projh = a.hb16 + NHC;
    a.w1t   = a.projh + (size_t)NNODES * 64;
    a.w2t   = a.w1t + 256 * 128;
    a.wpt   = a.w2t + 256 * 256;
    a.asn   = (float*)(a.wpt + 64 * 256);
    a.adn   = a.asn + (size_t)NNODES * 4;
    a.cnt   = (int*)(a.adn + (size_t)NNODES * 4);
    a.bucket = a.cnt + NNODES;

    // --- occupancy-derived cooperative grid (host queries: stream-free, deterministic) ---
    int dev = 0;
    hipGetDevice(&dev);
    int numCU = 0;
    hipDeviceGetAttribute(&numCU, hipDeviceAttributeMultiprocessorCount, dev);
    int coopOK = 0;
    hipDeviceGetAttribute(&coopOK, hipDeviceAttributeCooperativeLaunch, dev);
    int nb = 0;
    hipOccupancyMaxActiveBlocksPerMultiprocessor(&nb, mega, 256, 0);
    int grid = nb * numCU;
    if (grid > GRID_MAX) grid = GRID_MAX;

    hipError_t err = hipErrorUnknown;
    if (coopOK && grid >= NGRAPH) {
        void* params[] = { &a };
        err = hipLaunchCooperativeKernel((const void*)mega, dim3(grid), dim3(256),
                                         params, 0, stream);
    }
    if (err != hipSuccess) {
        (void)hipGetLastError();  // clear error state
        // fallback: known-good 8-kernel sequence (R10 structure)
        k_prep <<<(114688 + NNODES + 255) / 256, 256, 0, stream>>>(a);
        k_g1s  <<<GEMM_BLKS + SCAT_BLKS, 256, 0, stream>>>(a);
        k_agg1 <<<(NNODES + 3) / 4, 256, 0, stream>>>(a);
        k_gemm2<<<GEMM_BLKS, 256, 0, stream>>>(a);
        k_agg2 <<<(NNODES + 3) / 4, 256, 0, stream>>>(a);
        k_gemmp<<<GEMM_BLKS, 256, 0, stream>>>(a);
        k_aggp <<<(NNODES + 3) / 4, 256, 0, stream>>>(a);
        k_pool <<<NGRAPH, 256, 0, stream>>>(a);
    }
}